// Round 5
// baseline (150.135 us; speedup 1.0000x reference)
//
#include <hip/hip_runtime.h>

#define E_     5
#define H_     64
#define N_     64
#define MB_    64
#define N_DET_ 16
#define L_     8
#define DIA_   110
#define V_     (MB_*N_)        // 4096
#define NVOX_  (H_*N_*N_)      // 262144
#define K_     (DIA_*V_)       // 450560

// ---------------------------------------------------------------------------
// Kernel 1 (merged): blocks 0..1023 = bilinear-rotate + 6-bit quantize into
// the 1 MB gather table; block 1024 = probe attenuation cumsum + transmission.
// ---------------------------------------------------------------------------
__global__ __launch_bounds__(256) void k_prep(const float* __restrict__ grid,
                                              const float* __restrict__ xp,
                                              const float* __restrict__ pa,
                                              const int* __restrict__ theta_idx,
                                              unsigned* __restrict__ conc4,
                                              float* __restrict__ att_ws,
                                              float* __restrict__ out_trans)
{
    __shared__ float lac[V_];
    int tid = threadIdx.x;

    if (blockIdx.x < 1024) {
        // ---- rotation + quantization path ----
        int idx = blockIdx.x * 256 + tid;          // voxel index in [0, NVOX)
        int x = idx & 63;
        int y = (idx >> 6) & 63;
        int h = idx >> 12;

        float vals[E_];
        if (h == 0) {
            // conc_rot[:, 0:MB, :] = xp  (P_BLK == 0, m == y)
            #pragma unroll
            for (int e = 0; e < E_; ++e) vals[e] = xp[e * V_ + y * 64 + x];
        } else {
            int ti = theta_idx[0];
            float theta = (float)(-((double)ti * 6.283185307179586 / 200.0));
            float ct = cosf(theta), st = sinf(theta);
            const float c = 31.5f;
            float ys = (float)y - c, xs = (float)x - c;
            float ysrc = ct * ys - st * xs + c;
            float xsrc = st * ys + ct * xs + c;
            float y0 = floorf(ysrc), x0 = floorf(xsrc);
            float wy = ysrc - y0, wx = xsrc - x0;
            float y1 = y0 + 1.0f, x1 = x0 + 1.0f;

            bool by0 = (y0 >= 0.0f) && (y0 <= 63.0f);
            bool by1 = (y1 >= 0.0f) && (y1 <= 63.0f);
            bool bx0 = (x0 >= 0.0f) && (x0 <= 63.0f);
            bool bx1 = (x1 >= 0.0f) && (x1 <= 63.0f);

            int y0c = min(max((int)y0, 0), 63), y1c = min(max((int)y1, 0), 63);
            int x0c = min(max((int)x0, 0), 63), x1c = min(max((int)x1, 0), 63);

            float w00 = (1.0f - wy) * (1.0f - wx) * ((by0 && bx0) ? 1.0f : 0.0f);
            float w01 = (1.0f - wy) * wx          * ((by0 && bx1) ? 1.0f : 0.0f);
            float w10 = wy * (1.0f - wx)          * ((by1 && bx0) ? 1.0f : 0.0f);
            float w11 = wy * wx                   * ((by1 && bx1) ? 1.0f : 0.0f);

            #pragma unroll
            for (int e = 0; e < E_; ++e) {
                const float* base = grid + ((size_t)(e * 64 + h) << 12);
                vals[e] = w00 * base[y0c * 64 + x0c] + w01 * base[y0c * 64 + x1c]
                        + w10 * base[y1c * 64 + x0c] + w11 * base[y1c * 64 + x1c];
            }
        }

        unsigned q = 0;
        #pragma unroll
        for (int e = 0; e < E_; ++e)
            q |= ((unsigned)(vals[e] * 63.0f + 0.5f)) << (6 * e);
        conc4[idx] = q;
    } else {
        // ---- probe attenuation path (one block) ----
        float a0 = pa[0], a1 = pa[1], a2 = pa[2], a3 = pa[3], a4 = pa[4];
        #pragma unroll
        for (int c = 0; c < 16; ++c) {
            int o = c * 256 + tid;
            lac[o] = xp[o] * a0 + xp[V_ + o] * a1 + xp[2 * V_ + o] * a2
                   + xp[3 * V_ + o] * a3 + xp[4 * V_ + o] * a4;
        }
        __syncthreads();

        int wave = tid >> 6, lane = tid & 63;
        const float scale = 0.01f / 64.0f;   // CM / N
        for (int k = 0; k < 16; ++k) {
            int m = wave * 16 + k;
            float s = lac[m * 64 + lane];
            float own = s;
            #pragma unroll
            for (int off = 1; off < 64; off <<= 1) {
                float t = __shfl_up(s, off, 64);
                if (lane >= off) s += t;
            }
            att_ws[m * 64 + lane] = expf(-(s - own) * scale);   // exclusive cumsum
            if (lane == 63) out_trans[m] = 1.0e7f * expf(-s * scale);
        }
    }
}

// ---------------------------------------------------------------------------
// Kernel 2 (dominant): 8 (d,v) pairs per wave, lane<55 owns segments
// (2*lane, 2*lane+1). Structure tuned to keep the per-CU miss queue full:
//   - 16 coalesced 8-B nontemporal stream loads (all pairs)
//   - batch A: 8 gathers (pairs 0-3) issued, L1-bypassed, saddr form
//   - batch B: 8 gathers (pairs 4-7) issued
//   - s_waitcnt vmcnt(8): reduce batch A WHILE batch B is in flight
//   - s_waitcnt vmcnt(0): reduce batch B
// Reduction per pair: partial butterfly (bits 0-2) on 5 element sums,
// per-lane FL weighting (l=lane&7), final butterfly (bits 3-5).
// ---------------------------------------------------------------------------
__global__ __launch_bounds__(256) void k_main(const int* __restrict__ P_idx,
                                              const float* __restrict__ P_len,
                                              const unsigned* __restrict__ conc4,
                                              const float* __restrict__ FL,
                                              float* __restrict__ SAexp)
{
    int lane = threadIdx.x & 63;
    int wv = blockIdx.x * 4 + (threadIdx.x >> 6);   // wave id [0, 8192)
    int p0 = wv * 8;                                // first pair; d fixed for all 8
    int d  = p0 >> 12;
    int v0 = p0 & 4095;
    int l  = lane & 7;
    bool act = lane < 55;
    int off2 = act ? 2 * lane : 108;                // clamp keeps reads in-row

    float fll[E_];
    #pragma unroll
    for (int e = 0; e < E_; ++e) fll[e] = FL[e * L_ + l] * (1.0f / 63.0f);

    // ---- stage 1: all 16 stream loads (independent, in flight together) ----
    unsigned long long sii[8], sll[8];
    #pragma unroll
    for (int j = 0; j < 8; ++j) {
        size_t base = (size_t)d * K_ + (size_t)(v0 + j) * DIA_ + off2;  // 8B aligned
        sii[j] = __builtin_nontemporal_load((const unsigned long long*)(P_idx + base));
        sll[j] = __builtin_nontemporal_load((const unsigned long long*)(P_len + base));
    }

    // byte offsets into the 1 MB table (saddr-form gathers: 32-bit voffset)
    unsigned o0  = (unsigned)(sii[0] & 0xffffffffu) << 2, o1  = (unsigned)(sii[0] >> 32) << 2;
    unsigned o2  = (unsigned)(sii[1] & 0xffffffffu) << 2, o3  = (unsigned)(sii[1] >> 32) << 2;
    unsigned o4  = (unsigned)(sii[2] & 0xffffffffu) << 2, o5  = (unsigned)(sii[2] >> 32) << 2;
    unsigned o6  = (unsigned)(sii[3] & 0xffffffffu) << 2, o7  = (unsigned)(sii[3] >> 32) << 2;
    unsigned o8  = (unsigned)(sii[4] & 0xffffffffu) << 2, o9  = (unsigned)(sii[4] >> 32) << 2;
    unsigned o10 = (unsigned)(sii[5] & 0xffffffffu) << 2, o11 = (unsigned)(sii[5] >> 32) << 2;
    unsigned o12 = (unsigned)(sii[6] & 0xffffffffu) << 2, o13 = (unsigned)(sii[6] >> 32) << 2;
    unsigned o14 = (unsigned)(sii[7] & 0xffffffffu) << 2, o15 = (unsigned)(sii[7] >> 32) << 2;

    unsigned g0, g1, g2, g3, g4, g5, g6, g7, g8, g9, g10, g11, g12, g13, g14, g15;
    // batch A issue (pairs 0-3)
    asm volatile("global_load_dword %0, %8, %16 sc0\n\t"
                 "global_load_dword %1, %9, %16 sc0\n\t"
                 "global_load_dword %2, %10, %16 sc0\n\t"
                 "global_load_dword %3, %11, %16 sc0\n\t"
                 "global_load_dword %4, %12, %16 sc0\n\t"
                 "global_load_dword %5, %13, %16 sc0\n\t"
                 "global_load_dword %6, %14, %16 sc0\n\t"
                 "global_load_dword %7, %15, %16 sc0"
                 : "=&v"(g0), "=&v"(g1), "=&v"(g2), "=&v"(g3),
                   "=&v"(g4), "=&v"(g5), "=&v"(g6), "=&v"(g7)
                 : "v"(o0), "v"(o1), "v"(o2), "v"(o3),
                   "v"(o4), "v"(o5), "v"(o6), "v"(o7), "s"(conc4));
    // batch B issue (pairs 4-7)
    asm volatile("global_load_dword %0, %8, %16 sc0\n\t"
                 "global_load_dword %1, %9, %16 sc0\n\t"
                 "global_load_dword %2, %10, %16 sc0\n\t"
                 "global_load_dword %3, %11, %16 sc0\n\t"
                 "global_load_dword %4, %12, %16 sc0\n\t"
                 "global_load_dword %5, %13, %16 sc0\n\t"
                 "global_load_dword %6, %14, %16 sc0\n\t"
                 "global_load_dword %7, %15, %16 sc0"
                 : "=&v"(g8), "=&v"(g9), "=&v"(g10), "=&v"(g11),
                   "=&v"(g12), "=&v"(g13), "=&v"(g14), "=&v"(g15)
                 : "v"(o8), "v"(o9), "v"(o10), "v"(o11),
                   "v"(o12), "v"(o13), "v"(o14), "v"(o15), "s"(conc4));

    float ww[16];
    #pragma unroll
    for (int j = 0; j < 8; ++j) {
        float w0 = __uint_as_float((unsigned)(sll[j] & 0xffffffffu));
        float w1 = __uint_as_float((unsigned)(sll[j] >> 32));
        ww[2 * j]     = act ? w0 : 0.0f;
        ww[2 * j + 1] = act ? w1 : 0.0f;
    }

    float att[8];

    // ---- drain A only (B stays in flight), reduce pairs 0-3 ----
    asm volatile("s_waitcnt vmcnt(8)"
                 : "+v"(g0), "+v"(g1), "+v"(g2), "+v"(g3),
                   "+v"(g4), "+v"(g5), "+v"(g6), "+v"(g7));
    {
        unsigned qq[8] = {g0, g1, g2, g3, g4, g5, g6, g7};
        #pragma unroll
        for (int j = 0; j < 4; ++j) {
            float t0 = 0.f, t1 = 0.f, t2 = 0.f, t3 = 0.f, t4 = 0.f;
            #pragma unroll
            for (int hh = 0; hh < 2; ++hh) {
                unsigned q = qq[2 * j + hh];
                float w = ww[2 * j + hh];
                t0 += (float)( q        & 63u) * w;
                t1 += (float)((q >>  6) & 63u) * w;
                t2 += (float)((q >> 12) & 63u) * w;
                t3 += (float)((q >> 18) & 63u) * w;
                t4 += (float)( q >> 24        ) * w;
            }
            #pragma unroll
            for (int o = 1; o <= 4; o <<= 1) {
                t0 += __shfl_xor(t0, o, 64);
                t1 += __shfl_xor(t1, o, 64);
                t2 += __shfl_xor(t2, o, 64);
                t3 += __shfl_xor(t3, o, 64);
                t4 += __shfl_xor(t4, o, 64);
            }
            float a = t0 * fll[0] + t1 * fll[1] + t2 * fll[2] + t3 * fll[3] + t4 * fll[4];
            #pragma unroll
            for (int o = 8; o <= 32; o <<= 1)
                a += __shfl_xor(a, o, 64);
            att[j] = a;
        }
    }

    // ---- drain B, reduce pairs 4-7 ----
    asm volatile("s_waitcnt vmcnt(0)"
                 : "+v"(g8), "+v"(g9), "+v"(g10), "+v"(g11),
                   "+v"(g12), "+v"(g13), "+v"(g14), "+v"(g15));
    {
        unsigned qq[8] = {g8, g9, g10, g11, g12, g13, g14, g15};
        #pragma unroll
        for (int j = 0; j < 4; ++j) {
            float t0 = 0.f, t1 = 0.f, t2 = 0.f, t3 = 0.f, t4 = 0.f;
            #pragma unroll
            for (int hh = 0; hh < 2; ++hh) {
                unsigned q = qq[2 * j + hh];
                float w = ww[8 + 2 * j + hh];
                t0 += (float)( q        & 63u) * w;
                t1 += (float)((q >>  6) & 63u) * w;
                t2 += (float)((q >> 12) & 63u) * w;
                t3 += (float)((q >> 18) & 63u) * w;
                t4 += (float)( q >> 24        ) * w;
            }
            #pragma unroll
            for (int o = 1; o <= 4; o <<= 1) {
                t0 += __shfl_xor(t0, o, 64);
                t1 += __shfl_xor(t1, o, 64);
                t2 += __shfl_xor(t2, o, 64);
                t3 += __shfl_xor(t3, o, 64);
                t4 += __shfl_xor(t4, o, 64);
            }
            float a = t0 * fll[0] + t1 * fll[1] + t2 * fll[2] + t3 * fll[3] + t4 * fll[4];
            #pragma unroll
            for (int o = 8; o <= 32; o <<= 1)
                a += __shfl_xor(a, o, 64);
            att[4 + j] = a;
        }
    }

    if (lane < 8) {
        size_t ob = ((size_t)(lane * N_DET_ + d) << 12) + v0;
        float4 oa, obv;
        oa.x  = expf(-att[0]); oa.y  = expf(-att[1]);
        oa.z  = expf(-att[2]); oa.w  = expf(-att[3]);
        obv.x = expf(-att[4]); obv.y = expf(-att[5]);
        obv.z = expf(-att[6]); obv.w = expf(-att[7]);
        *(float4*)&SAexp[ob]     = oa;
        *(float4*)&SAexp[ob + 4] = obv;
    }
}

// ---------------------------------------------------------------------------
// Kernel 3: SA mean over detectors + fluorescence weighting + n-reduction.
// ---------------------------------------------------------------------------
__global__ void k_out(const float* __restrict__ SAexp, const float* __restrict__ att_ws,
                      const float* __restrict__ xp, const float* __restrict__ dfl,
                      float* __restrict__ out)
{
    int l = blockIdx.x >> 6;
    int m = blockIdx.x & 63;
    int n = threadIdx.x;           // 0..63
    int v = m * 64 + n;

    float s = 0.0f;
    #pragma unroll
    for (int d = 0; d < N_DET_; ++d)
        s += SAexp[(size_t)(l * N_DET_ + d) * V_ + v];

    int elem = (l < 2) ? l : ((l >> 1) + 1);   // LINE_TO_ELEM = {0,1,2,2,3,3,4,4}
    float wgt = 1.0e7f * att_ws[v] * dfl[l] * xp[elem * V_ + v] * (1.0f / 16.0f);
    float val = wgt * s;

    #pragma unroll
    for (int off = 32; off; off >>= 1) val += __shfl_xor(val, off, 64);
    if (n == 0) out[l * 64 + m] = val;
}

// ---------------------------------------------------------------------------
extern "C" void kernel_launch(void* const* d_in, const int* in_sizes, int n_in,
                              void* d_out, int out_size, void* d_ws, size_t ws_size,
                              hipStream_t stream)
{
    const float* grid  = (const float*)d_in[0];   // (E,H,N,N)
    const float* xp    = (const float*)d_in[1];   // (E,MB,N)
    const float* P_len = (const float*)d_in[2];   // (N_DET,K)
    const float* dfl   = (const float*)d_in[3];   // (L,)
    const float* FL    = (const float*)d_in[4];   // (E,L)
    const float* pa    = (const float*)d_in[5];   // (E,)
    const int*   P_idx = (const int*)d_in[6];     // (N_DET,K)
    const int*   tidx  = (const int*)d_in[7];     // scalar

    float* out = (float*)d_out;                   // [fl_signal(8*64) | trans(64)]

    char* ws = (char*)d_ws;
    unsigned* conc4 = (unsigned*)ws;                          // 1 MB (NVOX*4 B)
    float* att_ws = (float*)(ws + (size_t)NVOX_ * 4);         // 16 KB
    float* SAexp  = (float*)(ws + (size_t)NVOX_ * 4 + V_ * 4);// 2 MB

    k_prep<<<1025, 256, 0, stream>>>(grid, xp, pa, tidx, conc4, att_ws,
                                     out + L_ * MB_);
    k_main<<<8192 / 4, 256, 0, stream>>>(P_idx, P_len, conc4, FL, SAexp);
    k_out <<<L_ * MB_, 64, 0, stream>>>(SAexp, att_ws, xp, dfl, out);
}

// Round 6
// 146.445 us; speedup vs baseline: 1.0252x; 1.0252x over previous
//
#include <hip/hip_runtime.h>
#include <hip/hip_fp16.h>

#define E_     5
#define H_     64
#define N_     64
#define MB_    64
#define N_DET_ 16
#define L_     8
#define DIA_   110
#define V_     (MB_*N_)        // 4096
#define NVOX_  (H_*N_*N_)      // 262144
#define K_     (DIA_*V_)       // 450560

// ---------------------------------------------------------------------------
// Kernel 1 (merged): blocks 0..255 = LDS-staged bilinear rotate + 6-bit
// quantize into the 1 MB gather table (block b: h = b>>2, quarter = b&3;
// all 5 element planes staged to LDS as fp16 -> divergent rotated-line reads
// become conflict-free LDS reads). Block 256 = probe attenuation + transmission.
// ---------------------------------------------------------------------------
__global__ __launch_bounds__(256) void k_prep(const float* __restrict__ grid,
                                              const float* __restrict__ xp,
                                              const float* __restrict__ pa,
                                              const int* __restrict__ theta_idx,
                                              unsigned* __restrict__ conc4,
                                              float* __restrict__ att_ws,
                                              float* __restrict__ out_trans)
{
    __shared__ __half pl[E_][4096];   // 40 KB: 5 staged planes (fp16)
    __shared__ float lac[V_];         // 16 KB: attenuation path only
    int tid = threadIdx.x;

    if (blockIdx.x < 256) {
        int h = blockIdx.x >> 2;          // 0..63
        int q = blockIdx.x & 3;           // quarter of the plane

        if (h == 0) {
            // conc_rot[:, 0:MB, :] = xp  (P_BLK == 0): no rotation needed.
            #pragma unroll
            for (int c = 0; c < 4; ++c) {
                int p = q * 1024 + c * 256 + tid;     // p = y*64 + x
                unsigned w = 0;
                #pragma unroll
                for (int e = 0; e < E_; ++e)
                    w |= ((unsigned)(xp[e * V_ + p] * 63.0f + 0.5f)) << (6 * e);
                conc4[p] = w;
            }
            return;
        }

        // ---- stage: 5 coalesced planes -> LDS fp16 ----
        #pragma unroll
        for (int e = 0; e < E_; ++e) {
            const float4* src = (const float4*)(grid + ((size_t)(e * 64 + h) << 12));
            #pragma unroll
            for (int c = 0; c < 4; ++c) {
                int p4 = c * 256 + tid;               // float4 index, 0..1023
                float4 f = src[p4];
                pl[e][p4 * 4 + 0] = __float2half(f.x);
                pl[e][p4 * 4 + 1] = __float2half(f.y);
                pl[e][p4 * 4 + 2] = __float2half(f.z);
                pl[e][p4 * 4 + 3] = __float2half(f.w);
            }
        }
        __syncthreads();

        int ti = theta_idx[0];
        float theta = (float)(-((double)ti * 6.283185307179586 / 200.0));
        float ct = cosf(theta), st = sinf(theta);
        const float c0 = 31.5f;

        #pragma unroll
        for (int c = 0; c < 4; ++c) {
            int p = q * 1024 + c * 256 + tid;
            int x = p & 63;
            int y = p >> 6;
            float ys = (float)y - c0, xs = (float)x - c0;
            float ysrc = ct * ys - st * xs + c0;
            float xsrc = st * ys + ct * xs + c0;
            float y0 = floorf(ysrc), x0 = floorf(xsrc);
            float wy = ysrc - y0, wx = xsrc - x0;
            float y1 = y0 + 1.0f, x1 = x0 + 1.0f;

            bool by0 = (y0 >= 0.0f) && (y0 <= 63.0f);
            bool by1 = (y1 >= 0.0f) && (y1 <= 63.0f);
            bool bx0 = (x0 >= 0.0f) && (x0 <= 63.0f);
            bool bx1 = (x1 >= 0.0f) && (x1 <= 63.0f);

            int y0c = min(max((int)y0, 0), 63), y1c = min(max((int)y1, 0), 63);
            int x0c = min(max((int)x0, 0), 63), x1c = min(max((int)x1, 0), 63);

            float w00 = (1.0f - wy) * (1.0f - wx) * ((by0 && bx0) ? 1.0f : 0.0f);
            float w01 = (1.0f - wy) * wx          * ((by0 && bx1) ? 1.0f : 0.0f);
            float w10 = wy * (1.0f - wx)          * ((by1 && bx0) ? 1.0f : 0.0f);
            float w11 = wy * wx                   * ((by1 && bx1) ? 1.0f : 0.0f);

            int i00 = y0c * 64 + x0c, i01 = y0c * 64 + x1c;
            int i10 = y1c * 64 + x0c, i11 = y1c * 64 + x1c;

            unsigned w = 0;
            #pragma unroll
            for (int e = 0; e < E_; ++e) {
                float val = w00 * __half2float(pl[e][i00])
                          + w01 * __half2float(pl[e][i01])
                          + w10 * __half2float(pl[e][i10])
                          + w11 * __half2float(pl[e][i11]);
                w |= ((unsigned)(val * 63.0f + 0.5f)) << (6 * e);
            }
            conc4[(h << 12) + p] = w;
        }
    } else {
        // ---- probe attenuation path (one block) ----
        float a0 = pa[0], a1 = pa[1], a2 = pa[2], a3 = pa[3], a4 = pa[4];
        #pragma unroll
        for (int c = 0; c < 16; ++c) {
            int o = c * 256 + tid;
            lac[o] = xp[o] * a0 + xp[V_ + o] * a1 + xp[2 * V_ + o] * a2
                   + xp[3 * V_ + o] * a3 + xp[4 * V_ + o] * a4;
        }
        __syncthreads();

        int wave = tid >> 6, lane = tid & 63;
        const float scale = 0.01f / 64.0f;   // CM / N
        for (int k = 0; k < 16; ++k) {
            int m = wave * 16 + k;
            float s = lac[m * 64 + lane];
            float own = s;
            #pragma unroll
            for (int off = 1; off < 64; off <<= 1) {
                float t = __shfl_up(s, off, 64);
                if (lane >= off) s += t;
            }
            att_ws[m * 64 + lane] = expf(-(s - own) * scale);   // exclusive cumsum
            if (lane == 63) out_trans[m] = 1.0e7f * expf(-s * scale);
        }
    }
}

// ---------------------------------------------------------------------------
// Kernel 2 (dominant, UNCHANGED from round 5 — at the divergent-gather
// MSHR x latency wall, ~3.7 cyc/lane): 8 (d,v) pairs per wave, lane<55 owns
// segments (2*lane, 2*lane+1); 16 coalesced 8-B nontemporal stream loads;
// 2 batches of 8 L1-bypassed saddr gathers with staggered vmcnt drains.
// ---------------------------------------------------------------------------
__global__ __launch_bounds__(256) void k_main(const int* __restrict__ P_idx,
                                              const float* __restrict__ P_len,
                                              const unsigned* __restrict__ conc4,
                                              const float* __restrict__ FL,
                                              float* __restrict__ SAexp)
{
    int lane = threadIdx.x & 63;
    int wv = blockIdx.x * 4 + (threadIdx.x >> 6);   // wave id [0, 8192)
    int p0 = wv * 8;                                // first pair; d fixed for all 8
    int d  = p0 >> 12;
    int v0 = p0 & 4095;
    int l  = lane & 7;
    bool act = lane < 55;
    int off2 = act ? 2 * lane : 108;                // clamp keeps reads in-row

    float fll[E_];
    #pragma unroll
    for (int e = 0; e < E_; ++e) fll[e] = FL[e * L_ + l] * (1.0f / 63.0f);

    // ---- stage 1: all 16 stream loads (independent, in flight together) ----
    unsigned long long sii[8], sll[8];
    #pragma unroll
    for (int j = 0; j < 8; ++j) {
        size_t base = (size_t)d * K_ + (size_t)(v0 + j) * DIA_ + off2;  // 8B aligned
        sii[j] = __builtin_nontemporal_load((const unsigned long long*)(P_idx + base));
        sll[j] = __builtin_nontemporal_load((const unsigned long long*)(P_len + base));
    }

    // byte offsets into the 1 MB table (saddr-form gathers: 32-bit voffset)
    unsigned o0  = (unsigned)(sii[0] & 0xffffffffu) << 2, o1  = (unsigned)(sii[0] >> 32) << 2;
    unsigned o2  = (unsigned)(sii[1] & 0xffffffffu) << 2, o3  = (unsigned)(sii[1] >> 32) << 2;
    unsigned o4  = (unsigned)(sii[2] & 0xffffffffu) << 2, o5  = (unsigned)(sii[2] >> 32) << 2;
    unsigned o6  = (unsigned)(sii[3] & 0xffffffffu) << 2, o7  = (unsigned)(sii[3] >> 32) << 2;
    unsigned o8  = (unsigned)(sii[4] & 0xffffffffu) << 2, o9  = (unsigned)(sii[4] >> 32) << 2;
    unsigned o10 = (unsigned)(sii[5] & 0xffffffffu) << 2, o11 = (unsigned)(sii[5] >> 32) << 2;
    unsigned o12 = (unsigned)(sii[6] & 0xffffffffu) << 2, o13 = (unsigned)(sii[6] >> 32) << 2;
    unsigned o14 = (unsigned)(sii[7] & 0xffffffffu) << 2, o15 = (unsigned)(sii[7] >> 32) << 2;

    unsigned g0, g1, g2, g3, g4, g5, g6, g7, g8, g9, g10, g11, g12, g13, g14, g15;
    // batch A issue (pairs 0-3)
    asm volatile("global_load_dword %0, %8, %16 sc0\n\t"
                 "global_load_dword %1, %9, %16 sc0\n\t"
                 "global_load_dword %2, %10, %16 sc0\n\t"
                 "global_load_dword %3, %11, %16 sc0\n\t"
                 "global_load_dword %4, %12, %16 sc0\n\t"
                 "global_load_dword %5, %13, %16 sc0\n\t"
                 "global_load_dword %6, %14, %16 sc0\n\t"
                 "global_load_dword %7, %15, %16 sc0"
                 : "=&v"(g0), "=&v"(g1), "=&v"(g2), "=&v"(g3),
                   "=&v"(g4), "=&v"(g5), "=&v"(g6), "=&v"(g7)
                 : "v"(o0), "v"(o1), "v"(o2), "v"(o3),
                   "v"(o4), "v"(o5), "v"(o6), "v"(o7), "s"(conc4));
    // batch B issue (pairs 4-7)
    asm volatile("global_load_dword %0, %8, %16 sc0\n\t"
                 "global_load_dword %1, %9, %16 sc0\n\t"
                 "global_load_dword %2, %10, %16 sc0\n\t"
                 "global_load_dword %3, %11, %16 sc0\n\t"
                 "global_load_dword %4, %12, %16 sc0\n\t"
                 "global_load_dword %5, %13, %16 sc0\n\t"
                 "global_load_dword %6, %14, %16 sc0\n\t"
                 "global_load_dword %7, %15, %16 sc0"
                 : "=&v"(g8), "=&v"(g9), "=&v"(g10), "=&v"(g11),
                   "=&v"(g12), "=&v"(g13), "=&v"(g14), "=&v"(g15)
                 : "v"(o8), "v"(o9), "v"(o10), "v"(o11),
                   "v"(o12), "v"(o13), "v"(o14), "v"(o15), "s"(conc4));

    float ww[16];
    #pragma unroll
    for (int j = 0; j < 8; ++j) {
        float w0 = __uint_as_float((unsigned)(sll[j] & 0xffffffffu));
        float w1 = __uint_as_float((unsigned)(sll[j] >> 32));
        ww[2 * j]     = act ? w0 : 0.0f;
        ww[2 * j + 1] = act ? w1 : 0.0f;
    }

    float att[8];

    // ---- drain A only (B stays in flight), reduce pairs 0-3 ----
    asm volatile("s_waitcnt vmcnt(8)"
                 : "+v"(g0), "+v"(g1), "+v"(g2), "+v"(g3),
                   "+v"(g4), "+v"(g5), "+v"(g6), "+v"(g7));
    {
        unsigned qq[8] = {g0, g1, g2, g3, g4, g5, g6, g7};
        #pragma unroll
        for (int j = 0; j < 4; ++j) {
            float t0 = 0.f, t1 = 0.f, t2 = 0.f, t3 = 0.f, t4 = 0.f;
            #pragma unroll
            for (int hh = 0; hh < 2; ++hh) {
                unsigned q = qq[2 * j + hh];
                float w = ww[2 * j + hh];
                t0 += (float)( q        & 63u) * w;
                t1 += (float)((q >>  6) & 63u) * w;
                t2 += (float)((q >> 12) & 63u) * w;
                t3 += (float)((q >> 18) & 63u) * w;
                t4 += (float)( q >> 24        ) * w;
            }
            #pragma unroll
            for (int o = 1; o <= 4; o <<= 1) {
                t0 += __shfl_xor(t0, o, 64);
                t1 += __shfl_xor(t1, o, 64);
                t2 += __shfl_xor(t2, o, 64);
                t3 += __shfl_xor(t3, o, 64);
                t4 += __shfl_xor(t4, o, 64);
            }
            float a = t0 * fll[0] + t1 * fll[1] + t2 * fll[2] + t3 * fll[3] + t4 * fll[4];
            #pragma unroll
            for (int o = 8; o <= 32; o <<= 1)
                a += __shfl_xor(a, o, 64);
            att[j] = a;
        }
    }

    // ---- drain B, reduce pairs 4-7 ----
    asm volatile("s_waitcnt vmcnt(0)"
                 : "+v"(g8), "+v"(g9), "+v"(g10), "+v"(g11),
                   "+v"(g12), "+v"(g13), "+v"(g14), "+v"(g15));
    {
        unsigned qq[8] = {g8, g9, g10, g11, g12, g13, g14, g15};
        #pragma unroll
        for (int j = 0; j < 4; ++j) {
            float t0 = 0.f, t1 = 0.f, t2 = 0.f, t3 = 0.f, t4 = 0.f;
            #pragma unroll
            for (int hh = 0; hh < 2; ++hh) {
                unsigned q = qq[2 * j + hh];
                float w = ww[8 + 2 * j + hh];
                t0 += (float)( q        & 63u) * w;
                t1 += (float)((q >>  6) & 63u) * w;
                t2 += (float)((q >> 12) & 63u) * w;
                t3 += (float)((q >> 18) & 63u) * w;
                t4 += (float)( q >> 24        ) * w;
            }
            #pragma unroll
            for (int o = 1; o <= 4; o <<= 1) {
                t0 += __shfl_xor(t0, o, 64);
                t1 += __shfl_xor(t1, o, 64);
                t2 += __shfl_xor(t2, o, 64);
                t3 += __shfl_xor(t3, o, 64);
                t4 += __shfl_xor(t4, o, 64);
            }
            float a = t0 * fll[0] + t1 * fll[1] + t2 * fll[2] + t3 * fll[3] + t4 * fll[4];
            #pragma unroll
            for (int o = 8; o <= 32; o <<= 1)
                a += __shfl_xor(a, o, 64);
            att[4 + j] = a;
        }
    }

    if (lane < 8) {
        size_t ob = ((size_t)(lane * N_DET_ + d) << 12) + v0;
        float4 oa, obv;
        oa.x  = expf(-att[0]); oa.y  = expf(-att[1]);
        oa.z  = expf(-att[2]); oa.w  = expf(-att[3]);
        obv.x = expf(-att[4]); obv.y = expf(-att[5]);
        obv.z = expf(-att[6]); obv.w = expf(-att[7]);
        *(float4*)&SAexp[ob]     = oa;
        *(float4*)&SAexp[ob + 4] = obv;
    }
}

// ---------------------------------------------------------------------------
// Kernel 3: SA mean over detectors + fluorescence weighting + n-reduction.
// ---------------------------------------------------------------------------
__global__ void k_out(const float* __restrict__ SAexp, const float* __restrict__ att_ws,
                      const float* __restrict__ xp, const float* __restrict__ dfl,
                      float* __restrict__ out)
{
    int l = blockIdx.x >> 6;
    int m = blockIdx.x & 63;
    int n = threadIdx.x;           // 0..63
    int v = m * 64 + n;

    float s = 0.0f;
    #pragma unroll
    for (int d = 0; d < N_DET_; ++d)
        s += SAexp[(size_t)(l * N_DET_ + d) * V_ + v];

    int elem = (l < 2) ? l : ((l >> 1) + 1);   // LINE_TO_ELEM = {0,1,2,2,3,3,4,4}
    float wgt = 1.0e7f * att_ws[v] * dfl[l] * xp[elem * V_ + v] * (1.0f / 16.0f);
    float val = wgt * s;

    #pragma unroll
    for (int off = 32; off; off >>= 1) val += __shfl_xor(val, off, 64);
    if (n == 0) out[l * 64 + m] = val;
}

// ---------------------------------------------------------------------------
extern "C" void kernel_launch(void* const* d_in, const int* in_sizes, int n_in,
                              void* d_out, int out_size, void* d_ws, size_t ws_size,
                              hipStream_t stream)
{
    const float* grid  = (const float*)d_in[0];   // (E,H,N,N)
    const float* xp    = (const float*)d_in[1];   // (E,MB,N)
    const float* P_len = (const float*)d_in[2];   // (N_DET,K)
    const float* dfl   = (const float*)d_in[3];   // (L,)
    const float* FL    = (const float*)d_in[4];   // (E,L)
    const float* pa    = (const float*)d_in[5];   // (E,)
    const int*   P_idx = (const int*)d_in[6];     // (N_DET,K)
    const int*   tidx  = (const int*)d_in[7];     // scalar

    float* out = (float*)d_out;                   // [fl_signal(8*64) | trans(64)]

    char* ws = (char*)d_ws;
    unsigned* conc4 = (unsigned*)ws;                          // 1 MB (NVOX*4 B)
    float* att_ws = (float*)(ws + (size_t)NVOX_ * 4);         // 16 KB
    float* SAexp  = (float*)(ws + (size_t)NVOX_ * 4 + V_ * 4);// 2 MB

    k_prep<<<257, 256, 0, stream>>>(grid, xp, pa, tidx, conc4, att_ws,
                                    out + L_ * MB_);
    k_main<<<8192 / 4, 256, 0, stream>>>(P_idx, P_len, conc4, FL, SAexp);
    k_out <<<L_ * MB_, 64, 0, stream>>>(SAexp, att_ws, xp, dfl, out);
}